// Round 5
// baseline (217.943 us; speedup 1.0000x reference)
//
#include <hip/hip_runtime.h>
#include <stdint.h>

// BinConv2d: sign(x) conv3x3(pad1) sign(w) + batch-stat BN.
// Conv done as int8 implicit GEMM on MFMA (v_mfma_i32_32x32x32_i8), integer-exact.

#define HH 56
#define WW 56
#define CC 128
#define OO 128
#define NIMG 64
#define PIX (HH*WW)               // 3136
#define CNT (NIMG*PIX)            // 200704 per channel
#define TOT ((size_t)NIMG*OO*PIX) // 25690112

typedef int v4i  __attribute__((ext_vector_type(4)));
typedef int v16i __attribute__((ext_vector_type(16)));

// ws layout (bytes)
#define WS_WBT   0                 // 9*128*128 int8 (wbt[tap][o][c]) = 147456
#define WS_STATS 147456            // 128*{i64 sum, i64 sq} = 2048
#define WS_SS    149504            // float2[128] = 1024
#define WS_XI8   151552            // NHWC int8 sign(x): 64*3136*128 = 25690112 -> ends 25841664
#define WS_Y16   25841664          // TOT*int16 = 51380224 -> ends 77221888
#define WS_NEED  (25841664ULL + (size_t)TOT * 2)

// wbt[tap][o][c] int8, c contiguous (this is B^T: k-contiguous per output col)
__global__ void pack_w_i8(const float* __restrict__ w, char* __restrict__ wbt) {
    int t = blockIdx.x * 256 + threadIdx.x;
    if (t >= 1152) return;
    int tap = t >> 7, o = t & 127;
    const float* wp = w + (size_t)o * (CC * 9) + tap;   // OIHW: + c*9
    char* dst = wbt + (size_t)t * 128;
    #pragma unroll
    for (int chunk = 0; chunk < 8; ++chunk) {
        v4i v;
        #pragma unroll
        for (int wd = 0; wd < 4; ++wd) {
            unsigned u = 0;
            #pragma unroll
            for (int b = 0; b < 4; ++b) {
                int c = chunk * 16 + wd * 4 + b;
                float f = wp[c * 9];
                int s = (f > 0.f) - (f < 0.f);
                u |= (unsigned)((unsigned char)(char)s) << (8 * b);
            }
            v[wd] = (int)u;
        }
        *(v4i*)(dst + chunk * 16) = v;
    }
}

// xi8[n][h][w][c] int8 (NHWC, c contiguous = MFMA K dim)
__global__ void pack_x_i8(const float* __restrict__ x, char* __restrict__ xi8) {
    int n = blockIdx.y;
    int p = blockIdx.x * 256 + threadIdx.x;
    if (p >= PIX) return;
    const float* xp = x + (size_t)n * CC * PIX + p;
    char* dst = xi8 + ((size_t)n * PIX + p) * CC;
    #pragma unroll
    for (int chunk = 0; chunk < 8; ++chunk) {
        v4i v;
        #pragma unroll
        for (int wd = 0; wd < 4; ++wd) {
            unsigned u = 0;
            #pragma unroll
            for (int b = 0; b < 4; ++b) {
                int c = chunk * 16 + wd * 4 + b;
                float f = xp[(size_t)c * PIX];
                int s = (f > 0.f) - (f < 0.f);
                u |= (unsigned)((unsigned char)(char)s) << (8 * b);
            }
            v[wd] = (int)u;
        }
        *(v4i*)(dst + chunk * 16) = v;
    }
}

// MODE 0: stats only. MODE 1: stats + y16. MODE 2: normalized float out (fallback).
// Block 256 thr = 4 waves; wave = one 32-col N-tile; M = 4 image rows = 224 px = 7 M-tiles.
// A: LDS 6 rows x 58 cols x 128 int8 (zero halo). B: per-tap 16KB double-buffered (reg prefetch).
// MFMA frag layouts (32x32x32 i8): A row=lane&31, k=(lane>>5)*16+i (16B contiguous);
// B col=lane&31, same k split; C/D col=lane&31, row=(reg&3)+8*(reg>>2)+4*(lane>>5) [HW-verified].
template <int MODE>
__global__ __launch_bounds__(256, 2) void conv_mfma(
    const char* __restrict__ xi8, const char* __restrict__ wbt,
    unsigned long long* stats, const float2* __restrict__ ss,
    short* __restrict__ y16, float* __restrict__ out)
{
    __shared__ __align__(16) char Atile[6 * 58 * 128];   // 44544
    __shared__ __align__(16) char Btile[2][16384];

    const int strip = blockIdx.x;   // 0..13 (4 output rows each)
    const int n = blockIdx.y;       // image
    const int tid = threadIdx.x;
    const int lane = tid & 63;
    const int wave = tid >> 6;      // N-tile index 0..3
    const int ln31 = lane & 31;
    const int half16 = (lane >> 5) * 16;
    const int h0 = strip * 4;

    // ---- stage A: input rows h0-1..h0+4 into tile rows 0..5, cols 1..56; halo cols 0,57 zero
    {
        const char* xim = xi8 + (size_t)n * PIX * CC;
        for (int idx = tid; idx < 6 * 448; idx += 256) {
            int r = idx / 448, c = idx - r * 448;
            int gr = h0 - 1 + r;
            v4i v = {0, 0, 0, 0};
            if (gr >= 0 && gr < HH) v = *(const v4i*)(xim + ((size_t)gr * WW) * CC + c * 16);
            *(v4i*)(Atile + r * 7424 + 128 + c * 16) = v;
        }
        if (tid < 96) {   // 6 rows x 2 halo cols x 8 chunks
            int r = tid >> 4, rem = tid & 15;
            int off = r * 7424 + ((rem >> 3) ? 57 * 128 : 0) + (rem & 7) * 16;
            v4i z = {0, 0, 0, 0};
            *(v4i*)(Atile + off) = z;
        }
        #pragma unroll
        for (int p2 = 0; p2 < 4; ++p2)   // stage B tap 0
            *(v4i*)(Btile[0] + p2 * 4096 + tid * 16) = *(const v4i*)(wbt + p2 * 4096 + tid * 16);
    }

    // per-lane A base for each M-tile (pixel q = mt*32 + ln31; hh = q/56 via mul-shift)
    int abase[7];
    #pragma unroll
    for (int mt = 0; mt < 7; ++mt) {
        int q = mt * 32 + ln31;
        int hh = (q * 586) >> 15;
        int ww = q - hh * 56;
        abase[mt] = (hh * 58 + ww) * 128 + half16;
    }
    const int bidx = (wave * 32 + ln31) * 128 + half16;

    v16i acc[7];
    #pragma unroll
    for (int mt = 0; mt < 7; ++mt) {
        #pragma unroll
        for (int i = 0; i < 16; ++i) acc[mt][i] = 0;
    }

    __syncthreads();

    #pragma unroll
    for (int tap = 0; tap < 9; ++tap) {
        const int buf = tap & 1;
        v4i pre0, pre1, pre2, pre3;
        if (tap < 8) {   // prefetch next tap's B into registers (overlaps with MFMA below)
            const char* src = wbt + (size_t)(tap + 1) * 16384 + tid * 16;
            pre0 = *(const v4i*)(src);
            pre1 = *(const v4i*)(src + 4096);
            pre2 = *(const v4i*)(src + 8192);
            pre3 = *(const v4i*)(src + 12288);
        }
        const int tapoff = ((tap / 3) * 58 + (tap % 3)) * 128;
        const char* Bb = Btile[buf] + bidx;
        #pragma unroll
        for (int ks = 0; ks < 4; ++ks) {
            v4i bfrag = *(const v4i*)(Bb + ks * 32);
            #pragma unroll
            for (int mt = 0; mt < 7; ++mt) {
                v4i afrag = *(const v4i*)(Atile + abase[mt] + tapoff + ks * 32);
                acc[mt] = __builtin_amdgcn_mfma_i32_32x32x32_i8(afrag, bfrag, acc[mt], 0, 0, 0);
            }
        }
        if (tap < 8) {   // write prefetched B into the idle buffer
            char* dst = Btile[buf ^ 1] + tid * 16;
            *(v4i*)(dst)         = pre0;
            *(v4i*)(dst + 4096)  = pre1;
            *(v4i*)(dst + 8192)  = pre2;
            *(v4i*)(dst + 12288) = pre3;
        }
        __syncthreads();
    }

    // ---- epilogue: C reg (4g+j) -> pixel row q = mt*32 + 8g + 4*(lane>>5) + j, channel o
    const int o = wave * 32 + ln31;
    const int hl = lane >> 5;
    if (MODE != 2) {
        int ysum = 0, ysq = 0;
        size_t ybase = ((size_t)n * OO + o) * PIX + h0 * WW;
        #pragma unroll
        for (int mt = 0; mt < 7; ++mt) {
            #pragma unroll
            for (int g = 0; g < 4; ++g) {
                int y0 = acc[mt][4 * g + 0], y1 = acc[mt][4 * g + 1];
                int y2 = acc[mt][4 * g + 2], y3 = acc[mt][4 * g + 3];
                ysum += (y0 + y1) + (y2 + y3);
                ysq += y0 * y0 + y1 * y1 + y2 * y2 + y3 * y3;
                if (MODE == 1) {
                    unsigned lo = ((unsigned)y0 & 0xffffu) | ((unsigned)y1 << 16);
                    unsigned hi = ((unsigned)y2 & 0xffffu) | ((unsigned)y3 << 16);
                    int q0 = mt * 32 + g * 8 + hl * 4;
                    *(uint2*)(y16 + ybase + q0) = make_uint2(lo, hi);
                }
            }
        }
        int osum = __shfl_xor(ysum, 32);
        int osq  = __shfl_xor(ysq, 32);
        ysum += osum; ysq += osq;
        if (lane < 32) {
            atomicAdd(&stats[o * 2 + 0], (unsigned long long)(long long)ysum);
            atomicAdd(&stats[o * 2 + 1], (unsigned long long)(long long)ysq);
        }
    } else {
        float2 v = ss[o];
        size_t obase = ((size_t)n * OO + o) * PIX + h0 * WW;
        #pragma unroll
        for (int mt = 0; mt < 7; ++mt) {
            #pragma unroll
            for (int g = 0; g < 4; ++g) {
                int q0 = mt * 32 + g * 8 + hl * 4;
                float4 f;
                f.x = (float)acc[mt][4 * g + 0] * v.x + v.y;
                f.y = (float)acc[mt][4 * g + 1] * v.x + v.y;
                f.z = (float)acc[mt][4 * g + 2] * v.x + v.y;
                f.w = (float)acc[mt][4 * g + 3] * v.x + v.y;
                *(float4*)(out + obase + q0) = f;
            }
        }
    }
}

__global__ void finalize_kernel(const unsigned long long* __restrict__ stats,
                                const float* __restrict__ gamma,
                                const float* __restrict__ beta,
                                float2* __restrict__ ss) {
    int c = threadIdx.x;
    if (c >= 128) return;
    long long s = (long long)stats[c * 2 + 0];
    long long q = (long long)stats[c * 2 + 1];
    double mean = (double)s / (double)CNT;
    double var = (double)q / (double)CNT - mean * mean;
    double inv = 1.0 / sqrt(var + 1e-5);
    double g = (double)gamma[c];
    float sc = (float)(g * inv);
    float sh = (float)((double)beta[c] - mean * g * inv);
    ss[c] = make_float2(sc, sh);
}

// 8 elements/thread; 3136 % 8 == 0 so a group never crosses a channel boundary.
__global__ void norm_kernel(const short* __restrict__ y16,
                            const float2* __restrict__ ss,
                            float* __restrict__ out) {
    size_t g = (size_t)blockIdx.x * 256 + threadIdx.x;
    size_t e = g * 8;
    unsigned int chan = (unsigned int)((e / PIX) & 127);
    float2 v = ss[chan];
    int4 raw = *reinterpret_cast<const int4*>(y16 + e);
    float4 o0, o1;
    o0.x = (float)(short)(raw.x & 0xffff) * v.x + v.y;
    o0.y = (float)(short)(raw.x >> 16)    * v.x + v.y;
    o0.z = (float)(short)(raw.y & 0xffff) * v.x + v.y;
    o0.w = (float)(short)(raw.y >> 16)    * v.x + v.y;
    o1.x = (float)(short)(raw.z & 0xffff) * v.x + v.y;
    o1.y = (float)(short)(raw.z >> 16)    * v.x + v.y;
    o1.z = (float)(short)(raw.w & 0xffff) * v.x + v.y;
    o1.w = (float)(short)(raw.w >> 16)    * v.x + v.y;
    *reinterpret_cast<float4*>(out + e) = o0;
    *reinterpret_cast<float4*>(out + e + 4) = o1;
}

extern "C" void kernel_launch(void* const* d_in, const int* in_sizes, int n_in,
                              void* d_out, int out_size, void* d_ws, size_t ws_size,
                              hipStream_t stream) {
    const float* x     = (const float*)d_in[0];
    const float* wgt   = (const float*)d_in[1];
    const float* gamma = (const float*)d_in[2];
    const float* beta  = (const float*)d_in[3];
    float* out = (float*)d_out;
    char* ws = (char*)d_ws;

    char* wbt = ws + WS_WBT;
    unsigned long long* stats = (unsigned long long*)(ws + WS_STATS);
    float2* ssp = (float2*)(ws + WS_SS);
    char* xi8 = ws + WS_XI8;
    short* y16 = (short*)(ws + WS_Y16);

    hipMemsetAsync(stats, 0, 2048, stream);
    pack_w_i8<<<5, 256, 0, stream>>>(wgt, wbt);
    pack_x_i8<<<dim3(13, 64), 256, 0, stream>>>(x, xi8);

    if (ws_size >= WS_NEED) {
        conv_mfma<1><<<dim3(14, 64), 256, 0, stream>>>(xi8, wbt, stats, nullptr, y16, nullptr);
        finalize_kernel<<<1, 128, 0, stream>>>(stats, gamma, beta, ssp);
        norm_kernel<<<(unsigned)(TOT / 8 / 256), 256, 0, stream>>>(y16, ssp, out);
    } else {
        conv_mfma<0><<<dim3(14, 64), 256, 0, stream>>>(xi8, wbt, stats, nullptr, nullptr, nullptr);
        finalize_kernel<<<1, 128, 0, stream>>>(stats, gamma, beta, ssp);
        conv_mfma<2><<<dim3(14, 64), 256, 0, stream>>>(xi8, wbt, stats, ssp, nullptr, out);
    }
}

// Round 6
// 185.432 us; speedup vs baseline: 1.1753x; 1.1753x over previous
//
#include <hip/hip_runtime.h>
#include <stdint.h>

// BinConv2d: sign(x) conv3x3(pad1) sign(w) + batch-stat BN.
// Conv as int8 implicit GEMM on MFMA (v_mfma_i32_32x32x32_i8), integer-exact.
// R6: A-tile in LDS with k-outer layout (lane-stride 16B -> conflict-free);
//     B fragments loaded per-lane from global (L2-resident), prefetched 1 tap ahead.

#define HH 56
#define WW 56
#define CC 128
#define OO 128
#define NIMG 64
#define PIX (HH*WW)               // 3136
#define CNT (NIMG*PIX)            // 200704 per channel
#define TOT ((size_t)NIMG*OO*PIX) // 25690112

typedef int v4i  __attribute__((ext_vector_type(4)));
typedef int v16i __attribute__((ext_vector_type(16)));

// ws layout (bytes)
#define WS_WBT   0                 // 9*128*128 int8 (wbt[tap][o][c]) = 147456
#define WS_STATS 147456            // 128*{i64 sum, i64 sq} = 2048
#define WS_SS    149504            // float2[128] = 1024
#define WS_XI8   151552            // NHWC int8 sign(x): 64*3136*128 = 25690112 -> ends 25841664
#define WS_Y16   25841664          // TOT*int16 = 51380224 -> ends 77221888
#define WS_NEED  (25841664ULL + (size_t)TOT * 2)

// wbt[tap][o][c] int8, c contiguous (B^T: k-contiguous per output col)
__global__ void pack_w_i8(const float* __restrict__ w, char* __restrict__ wbt) {
    int t = blockIdx.x * 256 + threadIdx.x;
    if (t >= 1152) return;
    int tap = t >> 7, o = t & 127;
    const float* wp = w + (size_t)o * (CC * 9) + tap;   // OIHW: + c*9
    char* dst = wbt + (size_t)t * 128;
    #pragma unroll
    for (int chunk = 0; chunk < 8; ++chunk) {
        v4i v;
        #pragma unroll
        for (int wd = 0; wd < 4; ++wd) {
            unsigned u = 0;
            #pragma unroll
            for (int b = 0; b < 4; ++b) {
                int c = chunk * 16 + wd * 4 + b;
                float f = wp[c * 9];
                int s = (f > 0.f) - (f < 0.f);
                u |= (unsigned)((unsigned char)(char)s) << (8 * b);
            }
            v[wd] = (int)u;
        }
        *(v4i*)(dst + chunk * 16) = v;
    }
}

// xi8[n][h][w][c] int8 (NHWC, c contiguous = MFMA K dim)
__global__ void pack_x_i8(const float* __restrict__ x, char* __restrict__ xi8) {
    int n = blockIdx.y;
    int p = blockIdx.x * 256 + threadIdx.x;
    if (p >= PIX) return;
    const float* xp = x + (size_t)n * CC * PIX + p;
    char* dst = xi8 + ((size_t)n * PIX + p) * CC;
    #pragma unroll
    for (int chunk = 0; chunk < 8; ++chunk) {
        v4i v;
        #pragma unroll
        for (int wd = 0; wd < 4; ++wd) {
            unsigned u = 0;
            #pragma unroll
            for (int b = 0; b < 4; ++b) {
                int c = chunk * 16 + wd * 4 + b;
                float f = xp[(size_t)c * PIX];
                int s = (f > 0.f) - (f < 0.f);
                u |= (unsigned)((unsigned char)(char)s) << (8 * b);
            }
            v[wd] = (int)u;
        }
        *(v4i*)(dst + chunk * 16) = v;
    }
}

// MODE 0: stats only. MODE 1: stats + y16. MODE 2: normalized float out (fallback).
// Block 256 thr = 4 waves; wave = one 32-col N-tile; M = 4 image rows = 224 px = 7 M-tiles.
// A in LDS, K-OUTER layout: Av[kc][lp] of 16B, kc=0..7 (16B k-chunk), lp=0..347 (6x58 pixels,
// zero halo). Fragment read lane-stride = 16B -> conflict-free, no swizzle.
// B read per-lane from global wbt (L2-resident), next tap prefetched during MFMAs.
template <int MODE>
__global__ __launch_bounds__(256, 2) void conv_mfma(
    const char* __restrict__ xi8, const char* __restrict__ wbt,
    unsigned long long* stats, const float2* __restrict__ ss,
    short* __restrict__ y16, float* __restrict__ out)
{
    __shared__ __align__(16) char Atile[8 * 348 * 16];   // 44544 B

    const int strip = blockIdx.x;   // 0..13 (4 output rows each)
    const int n = blockIdx.y;       // image
    const int tid = threadIdx.x;
    const int lane = tid & 63;
    const int wave = tid >> 6;      // N-tile index 0..3
    const int ln31 = lane & 31;
    const int kbase = lane >> 5;    // k half (0/1)
    const int half16 = kbase * 16;
    const int h0 = strip * 4;

    // ---- stage A: Av[kc][lp] = xi8[n][h0-1+lp/58][lp%58-1][kc*16..+16) or 0 (halo)
    {
        const char* xim = xi8 + (size_t)n * PIX * CC;
        for (int idx = tid; idx < 8 * 348; idx += 256) {
            int kc = idx / 348, p = idx - kc * 348;
            int pr = p / 58, pc = p - pr * 58;
            int gr = h0 - 1 + pr, gw = pc - 1;
            v4i v = {0, 0, 0, 0};
            if (gr >= 0 && gr < HH && gw >= 0 && gw < WW)
                v = *(const v4i*)(xim + ((size_t)(gr * WW + gw)) * CC + kc * 16);
            *(v4i*)(Atile + idx * 16) = v;   // consecutive lanes -> consecutive 16B: conflict-free
        }
    }

    // per-mt linear pixel index lp0 (within-strip pixel q = mt*32 + ln31)
    int lpb[7];   // lp0 * 16 (byte offset of pixel within one kc plane)
    #pragma unroll
    for (int mt = 0; mt < 7; ++mt) {
        int q = mt * 32 + ln31;
        int hh = (q * 586) >> 15;        // q/56 for q<224
        int ww = q - hh * 56;
        lpb[mt] = (hh * 58 + ww) * 16;
    }
    // per-ks kc plane byte base: kc = ks*2 + kbase
    int ktb[4];
    #pragma unroll
    for (int ks = 0; ks < 4; ++ks) ktb[ks] = (ks * 2 + kbase) * 348 * 16;

    const char* bsrc = wbt + (wave * 32 + ln31) * 128 + half16;

    v16i acc[7];
    #pragma unroll
    for (int mt = 0; mt < 7; ++mt) {
        #pragma unroll
        for (int i = 0; i < 16; ++i) acc[mt][i] = 0;
    }

    __syncthreads();

    // preload tap 0 B fragments
    v4i b0 = *(const v4i*)(bsrc +  0);
    v4i b1 = *(const v4i*)(bsrc + 32);
    v4i b2 = *(const v4i*)(bsrc + 64);
    v4i b3 = *(const v4i*)(bsrc + 96);

    #pragma unroll
    for (int tap = 0; tap < 9; ++tap) {
        v4i n0, n1, n2, n3;
        if (tap < 8) {   // prefetch next tap's B (hidden under this tap's 28 MFMAs)
            const char* ns = bsrc + (tap + 1) * 16384;
            n0 = *(const v4i*)(ns +  0);
            n1 = *(const v4i*)(ns + 32);
            n2 = *(const v4i*)(ns + 64);
            n3 = *(const v4i*)(ns + 96);
        }
        const int dtapb = ((tap / 3) * 58 + (tap % 3)) * 16;
        #pragma unroll
        for (int mt = 0; mt < 7; ++mt) {
            const char* ap = Atile + lpb[mt] + dtapb;
            acc[mt] = __builtin_amdgcn_mfma_i32_32x32x32_i8(*(const v4i*)(ap + ktb[0]), b0, acc[mt], 0, 0, 0);
            acc[mt] = __builtin_amdgcn_mfma_i32_32x32x32_i8(*(const v4i*)(ap + ktb[1]), b1, acc[mt], 0, 0, 0);
            acc[mt] = __builtin_amdgcn_mfma_i32_32x32x32_i8(*(const v4i*)(ap + ktb[2]), b2, acc[mt], 0, 0, 0);
            acc[mt] = __builtin_amdgcn_mfma_i32_32x32x32_i8(*(const v4i*)(ap + ktb[3]), b3, acc[mt], 0, 0, 0);
        }
        if (tap < 8) { b0 = n0; b1 = n1; b2 = n2; b3 = n3; }
    }

    // ---- epilogue: C reg (4g+j) -> pixel q = mt*32 + 8g + 4*(lane>>5) + j, channel o
    const int o = wave * 32 + ln31;
    const int hl = kbase;
    if (MODE != 2) {
        int ysum = 0, ysq = 0;
        size_t ybase = ((size_t)n * OO + o) * PIX + h0 * WW;
        #pragma unroll
        for (int mt = 0; mt < 7; ++mt) {
            #pragma unroll
            for (int g = 0; g < 4; ++g) {
                int y0 = acc[mt][4 * g + 0], y1 = acc[mt][4 * g + 1];
                int y2 = acc[mt][4 * g + 2], y3 = acc[mt][4 * g + 3];
                ysum += (y0 + y1) + (y2 + y3);
                ysq += y0 * y0 + y1 * y1 + y2 * y2 + y3 * y3;
                if (MODE == 1) {
                    unsigned lo = ((unsigned)y0 & 0xffffu) | ((unsigned)y1 << 16);
                    unsigned hi = ((unsigned)y2 & 0xffffu) | ((unsigned)y3 << 16);
                    int q0 = mt * 32 + g * 8 + hl * 4;
                    *(uint2*)(y16 + ybase + q0) = make_uint2(lo, hi);
                }
            }
        }
        ysum += __shfl_xor(ysum, 32);
        ysq  += __shfl_xor(ysq, 32);
        if (lane < 32) {
            atomicAdd(&stats[o * 2 + 0], (unsigned long long)(long long)ysum);
            atomicAdd(&stats[o * 2 + 1], (unsigned long long)(long long)ysq);
        }
    } else {
        float2 v = ss[o];
        size_t obase = ((size_t)n * OO + o) * PIX + h0 * WW;
        #pragma unroll
        for (int mt = 0; mt < 7; ++mt) {
            #pragma unroll
            for (int g = 0; g < 4; ++g) {
                int q0 = mt * 32 + g * 8 + hl * 4;
                float4 f;
                f.x = (float)acc[mt][4 * g + 0] * v.x + v.y;
                f.y = (float)acc[mt][4 * g + 1] * v.x + v.y;
                f.z = (float)acc[mt][4 * g + 2] * v.x + v.y;
                f.w = (float)acc[mt][4 * g + 3] * v.x + v.y;
                *(float4*)(out + obase + q0) = f;
            }
        }
    }
}

__global__ void finalize_kernel(const unsigned long long* __restrict__ stats,
                                const float* __restrict__ gamma,
                                const float* __restrict__ beta,
                                float2* __restrict__ ss) {
    int c = threadIdx.x;
    if (c >= 128) return;
    long long s = (long long)stats[c * 2 + 0];
    long long q = (long long)stats[c * 2 + 1];
    double mean = (double)s / (double)CNT;
    double var = (double)q / (double)CNT - mean * mean;
    double inv = 1.0 / sqrt(var + 1e-5);
    double g = (double)gamma[c];
    float sc = (float)(g * inv);
    float sh = (float)((double)beta[c] - mean * g * inv);
    ss[c] = make_float2(sc, sh);
}

// 8 elements/thread; 3136 % 8 == 0 so a group never crosses a channel boundary.
__global__ void norm_kernel(const short* __restrict__ y16,
                            const float2* __restrict__ ss,
                            float* __restrict__ out) {
    size_t g = (size_t)blockIdx.x * 256 + threadIdx.x;
    size_t e = g * 8;
    unsigned int chan = (unsigned int)((e / PIX) & 127);
    float2 v = ss[chan];
    int4 raw = *reinterpret_cast<const int4*>(y16 + e);
    float4 o0, o1;
    o0.x = (float)(short)(raw.x & 0xffff) * v.x + v.y;
    o0.y = (float)(short)(raw.x >> 16)    * v.x + v.y;
    o0.z = (float)(short)(raw.y & 0xffff) * v.x + v.y;
    o0.w = (float)(short)(raw.y >> 16)    * v.x + v.y;
    o1.x = (float)(short)(raw.z & 0xffff) * v.x + v.y;
    o1.y = (float)(short)(raw.z >> 16)    * v.x + v.y;
    o1.z = (float)(short)(raw.w & 0xffff) * v.x + v.y;
    o1.w = (float)(short)(raw.w >> 16)    * v.x + v.y;
    *reinterpret_cast<float4*>(out + e) = o0;
    *reinterpret_cast<float4*>(out + e + 4) = o1;
}

extern "C" void kernel_launch(void* const* d_in, const int* in_sizes, int n_in,
                              void* d_out, int out_size, void* d_ws, size_t ws_size,
                              hipStream_t stream) {
    const float* x     = (const float*)d_in[0];
    const float* wgt   = (const float*)d_in[1];
    const float* gamma = (const float*)d_in[2];
    const float* beta  = (const float*)d_in[3];
    float* out = (float*)d_out;
    char* ws = (char*)d_ws;

    char* wbt = ws + WS_WBT;
    unsigned long long* stats = (unsigned long long*)(ws + WS_STATS);
    float2* ssp = (float2*)(ws + WS_SS);
    char* xi8 = ws + WS_XI8;
    short* y16 = (short*)(ws + WS_Y16);

    hipMemsetAsync(stats, 0, 2048, stream);
    pack_w_i8<<<5, 256, 0, stream>>>(wgt, wbt);
    pack_x_i8<<<dim3(13, 64), 256, 0, stream>>>(x, xi8);

    if (ws_size >= WS_NEED) {
        conv_mfma<1><<<dim3(14, 64), 256, 0, stream>>>(xi8, wbt, stats, nullptr, y16, nullptr);
        finalize_kernel<<<1, 128, 0, stream>>>(stats, gamma, beta, ssp);
        norm_kernel<<<(unsigned)(TOT / 8 / 256), 256, 0, stream>>>(y16, ssp, out);
    } else {
        conv_mfma<0><<<dim3(14, 64), 256, 0, stream>>>(xi8, wbt, stats, nullptr, nullptr, nullptr);
        finalize_kernel<<<1, 128, 0, stream>>>(stats, gamma, beta, ssp);
        conv_mfma<2><<<dim3(14, 64), 256, 0, stream>>>(xi8, wbt, stats, ssp, nullptr, out);
    }
}

// Round 8
// 180.645 us; speedup vs baseline: 1.2065x; 1.0265x over previous
//
#include <hip/hip_runtime.h>
#include <stdint.h>

// BinConv2d: sign(x) conv3x3(pad1) sign(w) + batch-stat BN.
// Conv as int8 implicit GEMM on MFMA (v_mfma_i32_32x32x32_i8), integer-exact.
// R8 = R7 with the B-fragment kc-stride bug fixed (kc stride is 2048B; frag ks at +ks*4096).

#define HH 56
#define WW 56
#define CC 128
#define OO 128
#define NIMG 64
#define PIX (HH*WW)               // 3136
#define CNT (NIMG*PIX)            // 200704 per channel
#define TOT ((size_t)NIMG*OO*PIX) // 25690112

typedef int v4i  __attribute__((ext_vector_type(4)));
typedef int v16i __attribute__((ext_vector_type(16)));

// ws layout (bytes)
#define WS_WBT   0                 // 9*8*128*16 int8 (wbt2[tap][kc][o][16]) = 147456
#define WS_STATS 147456            // 128*{i64 sum, i64 sq} = 2048
#define WS_SS    149504            // float2[128] = 1024
#define WS_XI8   151552            // NHWC int8 sign(x): 64*3136*128 = 25690112 -> ends 25841664
#define WS_Y16   25841664          // TOT*int16 = 51380224 -> ends 77221888
#define WS_NEED  (25841664ULL + (size_t)TOT * 2)

// wbt2[tap][kc][o] x 16B: k-outer so B-fragment loads are lane-consecutive 16B.
__global__ void pack_w_i8(const float* __restrict__ w, char* __restrict__ wbt) {
    int t = blockIdx.x * 256 + threadIdx.x;
    if (t >= 1152) return;
    int tap = t >> 7, o = t & 127;
    const float* wp = w + (size_t)o * (CC * 9) + tap;   // OIHW: + c*9
    #pragma unroll
    for (int kc = 0; kc < 8; ++kc) {
        v4i v;
        #pragma unroll
        for (int wd = 0; wd < 4; ++wd) {
            unsigned u = 0;
            #pragma unroll
            for (int b = 0; b < 4; ++b) {
                int c = kc * 16 + wd * 4 + b;
                float f = wp[c * 9];
                int s = (f > 0.f) - (f < 0.f);
                u |= (unsigned)((unsigned char)(char)s) << (8 * b);
            }
            v[wd] = (int)u;
        }
        *(v4i*)(wbt + (((size_t)tap * 8 + kc) * 128 + o) * 16) = v;
    }
}

// xi8[n][h][w][c] int8 (NHWC, c contiguous = MFMA K dim)
__global__ void pack_x_i8(const float* __restrict__ x, char* __restrict__ xi8) {
    int n = blockIdx.y;
    int p = blockIdx.x * 256 + threadIdx.x;
    if (p >= PIX) return;
    const float* xp = x + (size_t)n * CC * PIX + p;
    char* dst = xi8 + ((size_t)n * PIX + p) * CC;
    #pragma unroll
    for (int chunk = 0; chunk < 8; ++chunk) {
        v4i v;
        #pragma unroll
        for (int wd = 0; wd < 4; ++wd) {
            unsigned u = 0;
            #pragma unroll
            for (int b = 0; b < 4; ++b) {
                int c = chunk * 16 + wd * 4 + b;
                float f = xp[(size_t)c * PIX];
                int s = (f > 0.f) - (f < 0.f);
                u |= (unsigned)((unsigned char)(char)s) << (8 * b);
            }
            v[wd] = (int)u;
        }
        *(v4i*)(dst + chunk * 16) = v;
    }
}

// MODE 0: stats only. MODE 1: stats + y16. MODE 2: normalized float out (fallback).
// Block 256 thr = 4 waves; wave = one 32-col N-tile; M = 4 image rows = 224 px = 7 M-tiles.
// A in LDS, K-OUTER layout: Av[kc][lp] of 16B (lane-stride 16B reads: conflict-free).
// B per-lane from global wbt2 (L1/L2-resident, coalesced), next tap prefetched in regs.
template <int MODE>
__global__ __launch_bounds__(256, 2) void conv_mfma(
    const char* __restrict__ xi8, const char* __restrict__ wbt,
    unsigned long long* stats, const float2* __restrict__ ss,
    short* __restrict__ y16, float* __restrict__ out)
{
    __shared__ __align__(16) char Atile[8 * 348 * 16];   // 44544 B

    const int strip = blockIdx.x;   // 0..13 (4 output rows each)
    const int n = blockIdx.y;       // image
    const int tid = threadIdx.x;
    const int lane = tid & 63;
    const int wave = tid >> 6;      // N-tile index 0..3
    const int ln31 = lane & 31;
    const int kbase = lane >> 5;    // k half (0/1)
    const int h0 = strip * 4;

    // ---- stage A: Av[kc][lp] = xi8[n][h0-1+lp/58][lp%58-1][kc*16..+16) or 0 (halo)
    {
        const char* xim = xi8 + (size_t)n * PIX * CC;
        for (int idx = tid; idx < 8 * 348; idx += 256) {
            int kc = idx / 348, p = idx - kc * 348;
            int pr = p / 58, pc = p - pr * 58;
            int gr = h0 - 1 + pr, gw = pc - 1;
            v4i v = {0, 0, 0, 0};
            if (gr >= 0 && gr < HH && gw >= 0 && gw < WW)
                v = *(const v4i*)(xim + ((size_t)(gr * WW + gw)) * CC + kc * 16);
            *(v4i*)(Atile + idx * 16) = v;   // consecutive lanes -> consecutive 16B: conflict-free
        }
    }

    // per-mt pixel byte offset within a kc plane (q = mt*32 + ln31)
    int lpb[7];
    #pragma unroll
    for (int mt = 0; mt < 7; ++mt) {
        int q = mt * 32 + ln31;
        int hh = (q * 586) >> 15;        // q/56 for q<224
        int ww = q - hh * 56;
        lpb[mt] = (hh * 58 + ww) * 16;
    }
    // kc plane byte base per ks: kc = ks*2 + kbase
    const int kt0 = (0 * 2 + kbase) * 348 * 16;
    const int kt1 = (1 * 2 + kbase) * 348 * 16;
    const int kt2 = (2 * 2 + kbase) * 348 * 16;
    const int kt3 = (3 * 2 + kbase) * 348 * 16;

    // B source: wbt2[tap][kc][o][16], o = wave*32+ln31, kc = ks*2+kbase.
    // kc stride = 128*16 = 2048B -> fragment ks lives at bsrc + ks*2*2048 = bsrc + ks*4096.
    const char* bsrc = wbt + ((size_t)(kbase * 128) + (wave * 32 + ln31)) * 16;

    v16i acc[7];
    #pragma unroll
    for (int mt = 0; mt < 7; ++mt) {
        #pragma unroll
        for (int i = 0; i < 16; ++i) acc[mt][i] = 0;
    }

    __syncthreads();

    // preload tap 0 B fragments (each: lanes 0-31 consecutive 512B, lanes 32-63 at +2KB)
    v4i b0 = *(const v4i*)(bsrc + 0);
    v4i b1 = *(const v4i*)(bsrc + 4096);
    v4i b2 = *(const v4i*)(bsrc + 8192);
    v4i b3 = *(const v4i*)(bsrc + 12288);

    #pragma unroll
    for (int tap = 0; tap < 9; ++tap) {
        v4i n0, n1, n2, n3;
        if (tap < 8) {   // prefetch next tap's B (hidden under this tap's 28 MFMAs)
            const char* ns = bsrc + (size_t)(tap + 1) * 16384;
            n0 = *(const v4i*)(ns + 0);
            n1 = *(const v4i*)(ns + 4096);
            n2 = *(const v4i*)(ns + 8192);
            n3 = *(const v4i*)(ns + 12288);
        }
        const int dtapb = ((tap / 3) * 58 + (tap % 3)) * 16;
        // ks-outer / mt-inner: consecutive MFMAs use different acc -> 7 indep chains
        #pragma unroll
        for (int mt = 0; mt < 7; ++mt)
            acc[mt] = __builtin_amdgcn_mfma_i32_32x32x32_i8(
                *(const v4i*)(Atile + lpb[mt] + dtapb + kt0), b0, acc[mt], 0, 0, 0);
        #pragma unroll
        for (int mt = 0; mt < 7; ++mt)
            acc[mt] = __builtin_amdgcn_mfma_i32_32x32x32_i8(
                *(const v4i*)(Atile + lpb[mt] + dtapb + kt1), b1, acc[mt], 0, 0, 0);
        #pragma unroll
        for (int mt = 0; mt < 7; ++mt)
            acc[mt] = __builtin_amdgcn_mfma_i32_32x32x32_i8(
                *(const v4i*)(Atile + lpb[mt] + dtapb + kt2), b2, acc[mt], 0, 0, 0);
        #pragma unroll
        for (int mt = 0; mt < 7; ++mt)
            acc[mt] = __builtin_amdgcn_mfma_i32_32x32x32_i8(
                *(const v4i*)(Atile + lpb[mt] + dtapb + kt3), b3, acc[mt], 0, 0, 0);
        if (tap < 8) { b0 = n0; b1 = n1; b2 = n2; b3 = n3; }
    }

    // ---- epilogue: C reg (4g+j) -> pixel q = mt*32 + 8g + 4*(lane>>5) + j, channel o
    const int o = wave * 32 + ln31;
    const int hl = kbase;
    if (MODE != 2) {
        int ysum = 0, ysq = 0;
        size_t ybase = ((size_t)n * OO + o) * PIX + h0 * WW;
        #pragma unroll
        for (int mt = 0; mt < 7; ++mt) {
            #pragma unroll
            for (int g = 0; g < 4; ++g) {
                int y0 = acc[mt][4 * g + 0], y1 = acc[mt][4 * g + 1];
                int y2 = acc[mt][4 * g + 2], y3 = acc[mt][4 * g + 3];
                ysum += (y0 + y1) + (y2 + y3);
                ysq += y0 * y0 + y1 * y1 + y2 * y2 + y3 * y3;
                if (MODE == 1) {
                    unsigned lo = ((unsigned)y0 & 0xffffu) | ((unsigned)y1 << 16);
                    unsigned hi = ((unsigned)y2 & 0xffffu) | ((unsigned)y3 << 16);
                    int q0 = mt * 32 + g * 8 + hl * 4;
                    *(uint2*)(y16 + ybase + q0) = make_uint2(lo, hi);
                }
            }
        }
        ysum += __shfl_xor(ysum, 32);
        ysq  += __shfl_xor(ysq, 32);
        if (lane < 32) {
            atomicAdd(&stats[o * 2 + 0], (unsigned long long)(long long)ysum);
            atomicAdd(&stats[o * 2 + 1], (unsigned long long)(long long)ysq);
        }
    } else {
        float2 v = ss[o];
        size_t obase = ((size_t)n * OO + o) * PIX + h0 * WW;
        #pragma unroll
        for (int mt = 0; mt < 7; ++mt) {
            #pragma unroll
            for (int g = 0; g < 4; ++g) {
                int q0 = mt * 32 + g * 8 + hl * 4;
                float4 f;
                f.x = (float)acc[mt][4 * g + 0] * v.x + v.y;
                f.y = (float)acc[mt][4 * g + 1] * v.x + v.y;
                f.z = (float)acc[mt][4 * g + 2] * v.x + v.y;
                f.w = (float)acc[mt][4 * g + 3] * v.x + v.y;
                *(float4*)(out + obase + q0) = f;
            }
        }
    }
}

__global__ void finalize_kernel(const unsigned long long* __restrict__ stats,
                                const float* __restrict__ gamma,
                                const float* __restrict__ beta,
                                float2* __restrict__ ss) {
    int c = threadIdx.x;
    if (c >= 128) return;
    long long s = (long long)stats[c * 2 + 0];
    long long q = (long long)stats[c * 2 + 1];
    double mean = (double)s / (double)CNT;
    double var = (double)q / (double)CNT - mean * mean;
    double inv = 1.0 / sqrt(var + 1e-5);
    double g = (double)gamma[c];
    float sc = (float)(g * inv);
    float sh = (float)((double)beta[c] - mean * g * inv);
    ss[c] = make_float2(sc, sh);
}

// 8 elements/thread; 3136 % 8 == 0 so a group never crosses a channel boundary.
__global__ void norm_kernel(const short* __restrict__ y16,
                            const float2* __restrict__ ss,
                            float* __restrict__ out) {
    size_t g = (size_t)blockIdx.x * 256 + threadIdx.x;
    size_t e = g * 8;
    unsigned int chan = (unsigned int)((e / PIX) & 127);
    float2 v = ss[chan];
    int4 raw = *reinterpret_cast<const int4*>(y16 + e);
    float4 o0, o1;
    o0.x = (float)(short)(raw.x & 0xffff) * v.x + v.y;
    o0.y = (float)(short)(raw.x >> 16)    * v.x + v.y;
    o0.z = (float)(short)(raw.y & 0xffff) * v.x + v.y;
    o0.w = (float)(short)(raw.y >> 16)    * v.x + v.y;
    o1.x = (float)(short)(raw.z & 0xffff) * v.x + v.y;
    o1.y = (float)(short)(raw.z >> 16)    * v.x + v.y;
    o1.z = (float)(short)(raw.w & 0xffff) * v.x + v.y;
    o1.w = (float)(short)(raw.w >> 16)    * v.x + v.y;
    *reinterpret_cast<float4*>(out + e) = o0;
    *reinterpret_cast<float4*>(out + e + 4) = o1;
}

extern "C" void kernel_launch(void* const* d_in, const int* in_sizes, int n_in,
                              void* d_out, int out_size, void* d_ws, size_t ws_size,
                              hipStream_t stream) {
    const float* x     = (const float*)d_in[0];
    const float* wgt   = (const float*)d_in[1];
    const float* gamma = (const float*)d_in[2];
    const float* beta  = (const float*)d_in[3];
    float* out = (float*)d_out;
    char* ws = (char*)d_ws;

    char* wbt = ws + WS_WBT;
    unsigned long long* stats = (unsigned long long*)(ws + WS_STATS);
    float2* ssp = (float2*)(ws + WS_SS);
    char* xi8 = ws + WS_XI8;
    short* y16 = (short*)(ws + WS_Y16);

    hipMemsetAsync(stats, 0, 2048, stream);
    pack_w_i8<<<5, 256, 0, stream>>>(wgt, wbt);
    pack_x_i8<<<dim3(13, 64), 256, 0, stream>>>(x, xi8);

    if (ws_size >= WS_NEED) {
        conv_mfma<1><<<dim3(14, 64), 256, 0, stream>>>(xi8, wbt, stats, nullptr, y16, nullptr);
        finalize_kernel<<<1, 128, 0, stream>>>(stats, gamma, beta, ssp);
        norm_kernel<<<(unsigned)(TOT / 8 / 256), 256, 0, stream>>>(y16, ssp, out);
    } else {
        conv_mfma<0><<<dim3(14, 64), 256, 0, stream>>>(xi8, wbt, stats, nullptr, nullptr, nullptr);
        finalize_kernel<<<1, 128, 0, stream>>>(stats, gamma, beta, ssp);
        conv_mfma<2><<<dim3(14, 64), 256, 0, stream>>>(xi8, wbt, stats, ssp, nullptr, out);
    }
}